// Round 12
// baseline (24.469 us; speedup 1.0000x reference)
//
#include <hip/hip_runtime.h>
#include <hip/hip_bf16.h>

#define NB 65536
#define ND 8
#define NE 16
#define NH 80
#define NF 9
#define NV 100000
#define NIN 160
#define WND 2048          // samples per window
#define NWND (NB / WND)   // 32 windows; grid = 32*8 = 256 = 1 block/CU

typedef __attribute__((ext_vector_type(8))) short short8;    // 8 bf16 (4 VGPRs)
typedef __attribute__((ext_vector_type(4))) float float4v;   // MFMA acc

__device__ inline unsigned short f2bf(float x) {   // RNE f32->bf16 (scalar)
  unsigned int u = __float_as_uint(x);
  return (unsigned short)((u + 0x7fffu + ((u >> 16) & 1u)) >> 16);
}
__device__ inline unsigned int cvt2(float x, float y) {  // HW v_cvt_pk path
  union { __hip_bfloat162 h; unsigned int u; } cv;
  cv.h = __float22bfloat162_rn(make_float2(x, y));
  return cv.u;
}

// Single fused kernel, ALL-WAVE reg-staged double-buffered pipeline (T14-style):
// per iteration: issue gathers for tile k+1 into registers -> barrier ->
// MFMA+epilogue tile k from LDS -> cvt+write tile k+1 to sA[(k+1)&1].
// 128-row tiles, 8 waves, 1 block/CU; every wave issues memory every iteration.
__global__ __launch_bounds__(512, 2) void k_main(
    const int* __restrict__ pid, const int* __restrict__ feats,
    const float* __restrict__ emb_pid, const float* __restrict__ emb_feats,
    const float* __restrict__ sw1, const float* __restrict__ dw1,
    const float* __restrict__ sb1, const float* __restrict__ db1,
    const float* __restrict__ sw2, const float* __restrict__ dw2,
    const float* __restrict__ sb2, const float* __restrict__ db2,
    const float* __restrict__ dl_w, const float* __restrict__ dl_b,
    float* __restrict__ out) {
  const int d = blockIdx.x >> 5;    // same-window blocks stride-32 apart -> same XCD
  const int wnd = blockIdx.x & 31;
  const int t = threadIdx.x, wave = t >> 6, lane = t & 63;

  __shared__ unsigned short sA[2][128][168];      // 86016 B, double-buffered tile
  __shared__ unsigned short sBF[5][5][4][16][8];  // 25600 B  [nt][ks][q][col][e]
  __shared__ int sOrig[WND];                      // 8192 B
  __shared__ int scnt[4][8];

  // ---- phase 1: chain head (pid, 4 passes) + W1 star-merge + hoists ----
  const int bbase = wnd * WND + t;
  int pp[4];
#pragma unroll
  for (int pass = 0; pass < 4; ++pass) pp[pass] = pid[bbase + pass * 512];

  for (int i = t; i < NIN * NH; i += 512) {   // 25 per thread, coalesced
    int k = i / NH, n = i % NH;               // sw1/dw1 are [k][n] -> flat i
    float w = sw1[i] * dw1[d * (NIN * NH) + i];
    sBF[n >> 4][k >> 5][(k >> 3) & 3][n & 15][k & 7] = f2bf(w);
  }

  const float dlb = dl_b[0];
  float dlacc = dlb;
  unsigned int ep[8];
  {
    const float* __restrict__ row = emb_pid + (d + 1) * NE;
#pragma unroll
    for (int i = 0; i < NE; i += 2) {
      float x0 = fmaxf(row[i], 0.f), x1 = fmaxf(row[i + 1], 0.f);
      dlacc = fmaf(x0, dl_w[i], dlacc);
      dlacc = fmaf(x1, dl_w[i + 1], dlacc);
      ep[i >> 1] = cvt2(x0, x1);
    }
  }
  float b1l[5], w2l[5];
#pragma unroll
  for (int nt = 0; nt < 5; ++nt) {
    int h = nt * 16 + (lane & 15);
    b1l[nt] = sb1[h] + db1[d * NH + h];
    w2l[nt] = sw2[h] * dw2[d * NH + h];
  }
  const float b2 = sb2[0] + db2[d];

  if (d == 0) {  // padding rows: e_pid row is zeros -> logits = dl_b exactly
#pragma unroll
    for (int pass = 0; pass < 4; ++pass)
      if (pp[pass] == 0) out[bbase + pass * 512] = dlb;
  }

  // ---- phase 2: ballot-rank compaction, 4 passes ----
  const unsigned long long lt = (1ull << lane) - 1ull;
  int rr[4];
#pragma unroll
  for (int pass = 0; pass < 4; ++pass) {
    unsigned long long m = __ballot(pp[pass] == d + 1);
    if (lane == 0) scnt[pass][wave] = (int)__popcll(m);
    rr[pass] = (int)__popcll(m & lt);
  }
  __syncthreads();   // scnt + sBF visible
  int pbase[4], run = 0;
#pragma unroll
  for (int pass = 0; pass < 4; ++pass) {
    int bw = 0, tt = 0;
#pragma unroll
    for (int w = 0; w < 8; ++w) {
      int v = scnt[pass][w];
      if (w < wave) bw += v;
      tt += v;
    }
    pbase[pass] = run + bw;
    run += tt;
  }
  const int c = run;
#pragma unroll
  for (int pass = 0; pass < 4; ++pass)
    if (pp[pass] == d + 1) sOrig[pbase[pass] + rr[pass]] = bbase + pass * 512;
  __syncthreads();   // sOrig ready

  if (c == 0) return;                 // block-uniform
  const int ntiles = (c + 127) >> 7;  // 128-row tiles

  const int s = t >> 2, q = t & 3;    // 4 threads per sample, 128 samples/tile
  const int gl = lane & ~3;

  float4 vv[NF];                      // in-flight gather registers (36 VGPR)

  // issue the 9 gathers for tile at g0 (indices deduped via 4-lane shfl)
  auto stage_load = [&](int g0) {
    int ss = g0 + s; if (ss >= c) ss = c - 1;
    const int bb = sOrig[ss];
    const int fb = bb * NF;
    int ia = feats[fb + q];
    int ib = feats[fb + 4 + q];
    int ic = (q == 0) ? feats[fb + 8] : 0;
    int idx[NF];
#pragma unroll
    for (int f = 0; f < 4; ++f) idx[f] = __shfl(ia, gl + f);
#pragma unroll
    for (int f = 0; f < 4; ++f) idx[4 + f] = __shfl(ib, gl + f);
    idx[8] = __shfl(ic, gl);
#pragma unroll
    for (int f = 0; f < NF; ++f)
      vv[f] = *(const float4*)(emb_feats +
                               (size_t)((f * (NV + 1) + idx[f]) * NE + q * 4));
  };
  // relu/bf16-convert the in-flight registers and write tile to sA[buf]
  auto stage_write = [&](int buf) {
    if (q < 2) {  // e_pid columns 0..15 (bucket-uniform)
      unsigned int* dst = (unsigned int*)&sA[buf][s][0];
#pragma unroll
      for (int j = 0; j < 4; ++j) dst[q * 4 + j] = ep[q * 4 + j];
    }
#pragma unroll
    for (int f = 0; f < NF; ++f) {
      uint2 w;
      w.x = cvt2(fmaxf(vv[f].x, 0.f), fmaxf(vv[f].y, 0.f));
      w.y = cvt2(fmaxf(vv[f].z, 0.f), fmaxf(vv[f].w, 0.f));
      *(uint2*)((unsigned int*)&sA[buf][s][16 + f * 16] + q * 2) = w;
    }
  };

  // ---- prologue: tile 0 ----
  stage_load(0);
  stage_write(0);

  // ---- pipeline: load(k+1) || MFMA(k) || write(k+1) ----
  for (int k = 0; k < ntiles; ++k) {
    if (k + 1 < ntiles) stage_load((k + 1) << 7);   // issue early (T14)
    __syncthreads();                                 // sA[k&1] fully written
    const int g0 = k << 7;
    if (g0 + wave * 16 < c) {   // strip-skip for the ragged tail
      const int buf = k & 1;
      float4v acc[5];
#pragma unroll
      for (int nt = 0; nt < 5; ++nt)
        acc[nt] = (float4v){b1l[nt], b1l[nt], b1l[nt], b1l[nt]};
      const int arow = wave * 16 + (lane & 15);
      const int koff = (lane >> 4) * 8;
#pragma unroll
      for (int ks = 0; ks < 5; ++ks) {
        short8 af = *(const short8*)&sA[buf][arow][ks * 32 + koff];
#pragma unroll
        for (int nt = 0; nt < 5; ++nt) {
          short8 bf = *(const short8*)&sBF[nt][ks][lane >> 4][lane & 15][0];
          acc[nt] = __builtin_amdgcn_mfma_f32_16x16x32_bf16(af, bf, acc[nt], 0, 0, 0);
        }
      }
      float pr[4];
#pragma unroll
      for (int r = 0; r < 4; ++r) {
        float a2 = 0.f;
#pragma unroll
        for (int nt = 0; nt < 5; ++nt) a2 = fmaf(fmaxf(acc[nt][r], 0.f), w2l[nt], a2);
        pr[r] = a2;
      }
#pragma unroll
      for (int r = 0; r < 4; ++r) {
        pr[r] += __shfl_xor(pr[r], 1);
        pr[r] += __shfl_xor(pr[r], 2);
        pr[r] += __shfl_xor(pr[r], 4);
        pr[r] += __shfl_xor(pr[r], 8);
      }
      if ((lane & 15) == 0) {
        int srow2 = wave * 16 + (lane >> 4) * 4;
#pragma unroll
        for (int r = 0; r < 4; ++r) {
          int kk = g0 + srow2 + r;
          if (kk < c) out[sOrig[kk]] = pr[r] + b2 + dlacc;
        }
      }
    }
    if (k + 1 < ntiles) stage_write((k + 1) & 1);   // cvt+write under the same phase
  }
}

extern "C" void kernel_launch(void* const* d_in, const int* in_sizes, int n_in,
                              void* d_out, int out_size, void* d_ws, size_t ws_size,
                              hipStream_t stream) {
  const int*   pid      = (const int*)d_in[0];
  const int*   feats    = (const int*)d_in[1];
  const float* emb_pid  = (const float*)d_in[2];
  const float* emb_f    = (const float*)d_in[3];
  const float* sw1      = (const float*)d_in[4];
  const float* dw1      = (const float*)d_in[5];
  const float* sb1      = (const float*)d_in[6];
  const float* db1      = (const float*)d_in[7];
  const float* sw2      = (const float*)d_in[8];
  const float* dw2      = (const float*)d_in[9];
  const float* sb2      = (const float*)d_in[10];
  const float* db2      = (const float*)d_in[11];
  const float* dl_w     = (const float*)d_in[12];
  const float* dl_b     = (const float*)d_in[13];
  float* out = (float*)d_out;
  (void)d_ws; (void)ws_size;

  k_main<<<NWND * ND, 512, 0, stream>>>(pid, feats, emb_pid, emb_f, sw1, dw1,
                                        sb1, db1, sw2, dw2, sb2, db2, dl_w,
                                        dl_b, out);
}